// Round 11
// baseline (2805.411 us; speedup 1.0000x reference)
//
#include <hip/hip_runtime.h>
#include <hip/hip_fp16.h>
#include <math.h>

#define Nn 50000
#define Ff 16
#define Tt 12
#define Hh 64
#define Ee 1600000
#define Cc 80  // F + H

static __device__ __forceinline__ float sigmoidf_(float x) { return 1.0f / (1.0f + expf(-x)); }

// packed edge: low 16 bits = src node (N=50000 < 65536), high 16 = fp16 weight
static __device__ __forceinline__ void edec(unsigned pk, int& s, float& w) {
  s = (int)(pk & 0xffffu);
  w = __half2float(__ushort_as_half((unsigned short)(pk >> 16)));
}

// ---------------- CSR build ----------------
// dc[d] accumulates (count << 42) + round(ew * 2^21) in one u64 atomic.
__global__ void k_deg(const int* __restrict__ ei, const float* __restrict__ ew,
                      unsigned long long* __restrict__ dc) {
  int e = blockIdx.x * blockDim.x + threadIdx.x;
  if (e >= Ee) return;
  int d = ei[Ee + e];
  unsigned long long pk = (1ULL << 42) + (unsigned long long)(ew[e] * 2097152.0f + 0.5f);
  atomicAdd(&dc[d], pk);
}

__global__ void k_dis(const unsigned long long* __restrict__ dc,
                      float* __restrict__ dis, int* __restrict__ cnt) {
  int i = blockIdx.x * blockDim.x + threadIdx.x;
  if (i >= Nn) return;
  unsigned long long v = dc[i];
  cnt[i] = (int)(v >> 42);
  float deg = (float)(v & ((1ULL << 42) - 1)) * (1.0f / 2097152.0f);
  dis[i] = 1.0f / sqrtf(deg + 1.0f);
}

__global__ __launch_bounds__(1024) void k_scan(const int* __restrict__ cnt,
                                               int* __restrict__ rp, int* __restrict__ cur) {
  __shared__ int ss[1024];
  const int ITEMS = (Nn + 1023) / 1024;  // 49
  int t = threadIdx.x;
  int base = t * ITEMS;
  int sum = 0;
  for (int k = 0; k < ITEMS; k++) {
    int idx = base + k;
    if (idx < Nn) sum += cnt[idx];
  }
  ss[t] = sum;
  __syncthreads();
  for (int off = 1; off < 1024; off <<= 1) {
    int v = (t >= off) ? ss[t - off] : 0;
    __syncthreads();
    ss[t] += v;
    __syncthreads();
  }
  int run = ss[t] - sum;  // exclusive prefix
  for (int k = 0; k < ITEMS; k++) {
    int idx = base + k;
    if (idx < Nn) { rp[idx] = run; cur[idx] = run; run += cnt[idx]; }
  }
  if (t == 0) rp[Nn] = Ee;
}

// epack[pos] = u16 src | fp16 weight: one scattered 4-B store per edge
__global__ void k_scatter(const int* __restrict__ ei, const float* __restrict__ ew,
                          const float* __restrict__ dis, int* __restrict__ cur,
                          unsigned* __restrict__ epack) {
  int e = blockIdx.x * blockDim.x + threadIdx.x;
  if (e >= Ee) return;
  int s = ei[e];
  int d = ei[Ee + e];
  float w = ew[e] * dis[s] * dis[d];
  int pos = atomicAdd(&cur[d], 1);
  unsigned hw = (unsigned)__half_as_ushort(__float2half_rn(w));
  epack[pos] = (unsigned)s | (hw << 16);
}

// ---------------- x fp32 -> fp16 (once) ----------------
__global__ void k_cvt_x(const float* __restrict__ x, __half* __restrict__ x16) {
  size_t idx = (size_t)blockIdx.x * blockDim.x + threadIdx.x;
  const size_t total = (size_t)Nn * Ff * Tt;
  if (idx < total) x16[idx] = __float2half(x[idx]);
}

// ---------------- Px16[t][i][f] = (A_hat @ x): wave per node, 48 lanes x 8B per edge ----------------
__global__ __launch_bounds__(256) void k_agg_px(
    const float* __restrict__ x, const __half* __restrict__ x16, __half* __restrict__ Px16,
    const int* __restrict__ rp, const unsigned* __restrict__ epack,
    const float* __restrict__ dis) {
  int i = blockIdx.x * 4 + (threadIdx.x >> 6);
  if (i >= Nn) return;
  int lane = threadIdx.x & 63;
  const int R = Ff * Tt;  // 192
  const bool act = lane < 48;
  float d = dis[i], sn = d * d;
  float a0 = 0.f, a1 = 0.f, a2 = 0.f, a3 = 0.f;
  if (act) {
    float4 sv = *(const float4*)(x + (size_t)i * R + 4 * lane);  // self, fp32 exact
    a0 = sn * sv.x; a1 = sn * sv.y; a2 = sn * sv.z; a3 = sn * sv.w;
  }
  int jb = rp[i], je = rp[i + 1];
  for (int j = jb; j < je; j += 2) {
    int jc1 = min(j + 1, Ee - 1);
    int s0, s1; float w0, w1;
    edec(epack[j], s0, w0);
    edec(epack[jc1], s1, w1);
    if (j + 1 >= je) w1 = 0.f;
    if (act) {
      uint2 g0 = *(const uint2*)(x16 + (size_t)s0 * R + 4 * lane);
      uint2 g1 = *(const uint2*)(x16 + (size_t)s1 * R + 4 * lane);
      float2 p01 = __half22float2(*reinterpret_cast<const __half2*>(&g0.x));
      float2 p23 = __half22float2(*reinterpret_cast<const __half2*>(&g0.y));
      float2 q01 = __half22float2(*reinterpret_cast<const __half2*>(&g1.x));
      float2 q23 = __half22float2(*reinterpret_cast<const __half2*>(&g1.y));
      a0 = fmaf(w0, p01.x, a0); a1 = fmaf(w0, p01.y, a1);
      a2 = fmaf(w0, p23.x, a2); a3 = fmaf(w0, p23.y, a3);
      a0 = fmaf(w1, q01.x, a0); a1 = fmaf(w1, q01.y, a1);
      a2 = fmaf(w1, q23.x, a2); a3 = fmaf(w1, q23.y, a3);
    }
  }
  if (act) {
#pragma unroll
    for (int k = 0; k < 4; k++) {
      int cch = 4 * lane + k;           // channel = f*T + t
      int f = cch / Tt, tt = cch % Tt;
      float val = (k == 0) ? a0 : (k == 1) ? a1 : (k == 2) ? a2 : a3;
      Px16[(size_t)tt * Nn * Ff + (size_t)i * Ff + f] = __float2half(val);
    }
  }
}

// ---------------- aggregation: wave per node, 16 lanes/edge x 8B, 4 edges/instr ----------------
__global__ __launch_bounds__(256) void k_agg64v(
    const __half* __restrict__ v, __half* __restrict__ outv,
    const int* __restrict__ rp, const unsigned* __restrict__ epack,
    const float* __restrict__ dis) {
  int i = blockIdx.x * 4 + (threadIdx.x >> 6);
  if (i >= Nn) return;
  int lane = threadIdx.x & 63;
  int g = lane >> 4;   // edge slot 0..3
  int c = lane & 15;   // channel quad: 4c..4c+3
  float d = dis[i], sn = d * d;
  float a0, a1, a2, a3;
  {
    const uint2 gv = *(const uint2*)(v + (size_t)i * Hh + 4 * c);  // self
    float2 f01 = __half22float2(*reinterpret_cast<const __half2*>(&gv.x));
    float2 f23 = __half22float2(*reinterpret_cast<const __half2*>(&gv.y));
    float ws = (g == 0) ? sn : 0.f;
    a0 = ws * f01.x; a1 = ws * f01.y; a2 = ws * f23.x; a3 = ws * f23.y;
  }
  int jb = rp[i], je = rp[i + 1];
  for (int j0 = jb; j0 < je; j0 += 8) {
    int j1 = j0 + g;
    int j2 = j0 + 4 + g;
    int s1, s2; float w1, w2;
    edec(epack[min(j1, Ee - 1)], s1, w1);
    edec(epack[min(j2, Ee - 1)], s2, w2);
    if (j1 >= je) w1 = 0.f;
    if (j2 >= je) w2 = 0.f;
    const uint2 g1 = *(const uint2*)(v + (size_t)s1 * Hh + 4 * c);
    const uint2 g2 = *(const uint2*)(v + (size_t)s2 * Hh + 4 * c);
    float2 p01 = __half22float2(*reinterpret_cast<const __half2*>(&g1.x));
    float2 p23 = __half22float2(*reinterpret_cast<const __half2*>(&g1.y));
    float2 q01 = __half22float2(*reinterpret_cast<const __half2*>(&g2.x));
    float2 q23 = __half22float2(*reinterpret_cast<const __half2*>(&g2.y));
    a0 = fmaf(w1, p01.x, a0); a1 = fmaf(w1, p01.y, a1);
    a2 = fmaf(w1, p23.x, a2); a3 = fmaf(w1, p23.y, a3);
    a0 = fmaf(w2, q01.x, a0); a1 = fmaf(w2, q01.y, a1);
    a2 = fmaf(w2, q23.x, a2); a3 = fmaf(w2, q23.y, a3);
  }
  a0 += __shfl_xor(a0, 16, 64); a1 += __shfl_xor(a1, 16, 64);
  a2 += __shfl_xor(a2, 16, 64); a3 += __shfl_xor(a3, 16, 64);
  a0 += __shfl_xor(a0, 32, 64); a1 += __shfl_xor(a1, 32, 64);
  a2 += __shfl_xor(a2, 32, 64); a3 += __shfl_xor(a3, 32, 64);
  if (lane < 16) {
    __half2 h01, h23;
    h01.x = __float2half_rn(a0); h01.y = __float2half_rn(a1);
    h23.x = __float2half_rn(a2); h23.y = __float2half_rn(a3);
    uint2 st;
    st.x = *reinterpret_cast<unsigned int*>(&h01);
    st.y = *reinterpret_cast<unsigned int*>(&h23);
    *(uint2*)(outv + (size_t)i * Hh + 4 * c) = st;
  }
}

// shared helper: stage 16 nodes x 80 channels (fp16 sources) into fp32 LDS
static __device__ __forceinline__ void stage_x(
    float (*sX)[Cc], const __half* __restrict__ Px16t, const __half* __restrict__ P64,
    int i0, int tid) {
  if (tid < 160) {
    int n = tid / 10, r = tid % 10;
    int i = i0 + n;
    uint4 raw = make_uint4(0u, 0u, 0u, 0u);
    if (i < Nn) {
      raw = (r < 2) ? *(const uint4*)(Px16t + (size_t)i * Ff + r * 8)
                    : *(const uint4*)(P64 + (size_t)i * Hh + (r - 2) * 8);
    }
    float2 f0 = __half22float2(*reinterpret_cast<const __half2*>(&raw.x));
    float2 f1 = __half22float2(*reinterpret_cast<const __half2*>(&raw.y));
    float2 f2 = __half22float2(*reinterpret_cast<const __half2*>(&raw.z));
    float2 f3 = __half22float2(*reinterpret_cast<const __half2*>(&raw.w));
    float* dst = &sX[n][r * 8];
    dst[0] = f0.x; dst[1] = f0.y; dst[2] = f1.x; dst[3] = f1.y;
    dst[4] = f2.x; dst[5] = f2.y; dst[6] = f3.x; dst[7] = f3.y;
  }
}

// ---------------- GEMM z/r: (Wz[c],Wr[c],Wz[c+1],Wr[c+1]) packed as uint2 -> b64 reads ----------------
// NOTE: no waves-per-EU hint — the 2nd __launch_bounds__ arg forces a VGPR cap the
// compiler satisfies by spilling to scratch (GB-scale WRITE_SIZE). Measured r2/r6.
__global__ __launch_bounds__(256) void k_gemm_zr(
    const __half* __restrict__ Px16, const __half* __restrict__ Ph16,
    const __half* __restrict__ h16,
    const float* __restrict__ Wz, const float* __restrict__ bz,
    const float* __restrict__ Wr, const float* __restrict__ br,
    __half* __restrict__ zb16, __half* __restrict__ rh16, int tstep) {
  __shared__ uint2 sWzr[(Cc / 2) * Hh];  // 20 KB: {h2(z0,r0), h2(z1,r1)} per (c-pair, o)
  __shared__ float sX[16][Cc];           // 5 KB
  const int tid = threadIdx.x;
  const int i0 = blockIdx.x * 16;
  for (int q = tid; q < (Cc / 2) * Hh; q += 256) {
    int c2 = q / Hh, o = q % Hh;
    int c = 2 * c2;
    __half2 lo = __floats2half2_rn(Wz[c * Hh + o], Wr[c * Hh + o]);
    __half2 hi = __floats2half2_rn(Wz[(c + 1) * Hh + o], Wr[(c + 1) * Hh + o]);
    uint2 pk;
    pk.x = *reinterpret_cast<unsigned*>(&lo);
    pk.y = *reinterpret_cast<unsigned*>(&hi);
    sWzr[q] = pk;
  }
  stage_x(sX, Px16 + (size_t)tstep * Nn * Ff, Ph16, i0, tid);
  __syncthreads();
  const int wv = tid >> 6, o = tid & 63;
  float az[4] = {0, 0, 0, 0}, ar[4] = {0, 0, 0, 0};
  for (int c = 0; c < Cc; c += 4) {
    uint2 pa = sWzr[(c / 2) * Hh + o];
    uint2 pb = sWzr[(c / 2 + 1) * Hh + o];
    float2 w0 = __half22float2(*reinterpret_cast<__half2*>(&pa.x));
    float2 w1 = __half22float2(*reinterpret_cast<__half2*>(&pa.y));
    float2 w2 = __half22float2(*reinterpret_cast<__half2*>(&pb.x));
    float2 w3 = __half22float2(*reinterpret_cast<__half2*>(&pb.y));
#pragma unroll
    for (int nd = 0; nd < 4; nd++) {
      const float4 xv = *(const float4*)&sX[wv * 4 + nd][c];
      az[nd] = fmaf(xv.x, w0.x, fmaf(xv.y, w1.x, fmaf(xv.z, w2.x, fmaf(xv.w, w3.x, az[nd]))));
      ar[nd] = fmaf(xv.x, w0.y, fmaf(xv.y, w1.y, fmaf(xv.z, w2.y, fmaf(xv.w, w3.y, ar[nd]))));
    }
  }
  float bzo = bz[o], bro = br[o];
#pragma unroll
  for (int nd = 0; nd < 4; nd++) {
    int i = i0 + wv * 4 + nd;
    if (i < Nn) {
      float zv = sigmoidf_(az[nd] + bzo);
      float rv = sigmoidf_(ar[nd] + bro);
      float hv = __half2float(h16[(size_t)i * Hh + o]);
      zb16[(size_t)i * Hh + o] = __float2half(zv);
      rh16[(size_t)i * Hh + o] = __float2half(rv * hv);
    }
  }
}

// ---------------- GEMM h: Wh packed as __half2 c-pairs (reads halved, 15 KB LDS) ----------------
__global__ __launch_bounds__(256) void k_gemm_h(
    const __half* __restrict__ Px16, const __half* __restrict__ Prh16,
    const __half* __restrict__ zb16, float* __restrict__ h, __half* __restrict__ h16,
    __half* __restrict__ hs16,
    const float* __restrict__ Wh, const float* __restrict__ bh, int tstep) {
  __shared__ __half2 sWh[(Cc / 2) * Hh];  // 10 KB: {Wh[c][o], Wh[c+1][o]}
  __shared__ float sX[16][Cc];            // 5 KB
  const int tid = threadIdx.x;
  const int i0 = blockIdx.x * 16;
  for (int q = tid; q < (Cc / 2) * Hh; q += 256) {
    int c2 = q / Hh, o = q % Hh;
    int c = 2 * c2;
    sWh[q] = __floats2half2_rn(Wh[c * Hh + o], Wh[(c + 1) * Hh + o]);
  }
  stage_x(sX, Px16 + (size_t)tstep * Nn * Ff, Prh16, i0, tid);
  __syncthreads();
  const int wv = tid >> 6, o = tid & 63;
  float ah[4] = {0, 0, 0, 0};
  for (int c = 0; c < Cc; c += 4) {
    float2 wa = __half22float2(sWh[(c / 2) * Hh + o]);
    float2 wb = __half22float2(sWh[(c / 2 + 1) * Hh + o]);
#pragma unroll
    for (int nd = 0; nd < 4; nd++) {
      const float4 xv = *(const float4*)&sX[wv * 4 + nd][c];
      ah[nd] = fmaf(xv.x, wa.x, fmaf(xv.y, wa.y, fmaf(xv.z, wb.x, fmaf(xv.w, wb.y, ah[nd]))));
    }
  }
  float bho = bh[o];
  __half* hst = hs16 + (size_t)tstep * Nn * Hh;
#pragma unroll
  for (int nd = 0; nd < 4; nd++) {
    int i = i0 + wv * 4 + nd;
    if (i < Nn) {
      float hc = tanhf(ah[nd] + bho);
      float zv = __half2float(zb16[(size_t)i * Hh + o]);
      float hv = h[(size_t)i * Hh + o];
      float hn = zv * hv + (1.0f - zv) * hc;
      h[(size_t)i * Hh + o] = hn;
      __half hh = __float2half(hn);
      h16[(size_t)i * Hh + o] = hh;
      hst[(size_t)i * Hh + o] = hh;
    }
  }
}

// ---------------- attention + output: wave per node over T=12 history ----------------
// Round-7 form (VGPR 44, 55% occupancy). Both loop-interchange variants regressed:
// r8 full (12 acc) spilled to 256 VGPR / 3.6 GB scratch; r9 TB=4 hit 144 VGPR / 11% occ.
__global__ __launch_bounds__(256) void k_att(
    const __half* __restrict__ hs16, const float* __restrict__ Wa,
    const float* __restrict__ ba, const float* __restrict__ cv,
    const float* __restrict__ Wfc, const float* __restrict__ bfc,
    float* __restrict__ out) {
  __shared__ float sWa[Hh * Hh];      // 16 KB
  __shared__ float sH[4][Tt][Hh];     // 12 KB
  const int tid = threadIdx.x;
  {
    const float4* a4 = (const float4*)Wa;
    float4* sa4 = (float4*)sWa;
    for (int q = tid; q < (Hh * Hh) / 4; q += 256) sa4[q] = a4[q];
  }
  const int wv = tid >> 6, o = tid & 63;
  const int i = blockIdx.x * 4 + wv;
  if (i < Nn) {
#pragma unroll
    for (int t = 0; t < Tt; t++)
      sH[wv][t][o] = __half2float(hs16[(size_t)t * Nn * Hh + (size_t)i * Hh + o]);
  }
  __syncthreads();
  if (i >= Nn) return;
  float bao = ba[o], cvo = cv[o];
  float al[Tt];
#pragma unroll
  for (int t = 0; t < Tt; t++) {
    float sc = 0.f;
    for (int c = 0; c < Hh; c += 4) {
      const float4 hv4 = *(const float4*)&sH[wv][t][c];
      sc = fmaf(hv4.x, sWa[(c + 0) * Hh + o],
           fmaf(hv4.y, sWa[(c + 1) * Hh + o],
           fmaf(hv4.z, sWa[(c + 2) * Hh + o],
           fmaf(hv4.w, sWa[(c + 3) * Hh + o], sc))));
    }
    float ap = tanhf(sc + bao) * cvo;
#pragma unroll
    for (int off = 32; off >= 1; off >>= 1) ap += __shfl_xor(ap, off, 64);
    al[t] = ap;  // all lanes hold align[i][t]
  }
  float m = al[0];
#pragma unroll
  for (int t = 1; t < Tt; t++) m = fmaxf(m, al[t]);
  float s = 0.f;
#pragma unroll
  for (int t = 0; t < Tt; t++) { al[t] = expf(al[t] - m); s += al[t]; }
  float inv = 1.0f / s;
  float cx = 0.f;
#pragma unroll
  for (int t = 0; t < Tt; t++) cx = fmaf(al[t], sH[wv][t][o], cx);
  float p = cx * inv * Wfc[o];
#pragma unroll
  for (int off = 32; off >= 1; off >>= 1) p += __shfl_xor(p, off, 64);
  if (o == 0) out[i] = p + bfc[0];
}

extern "C" void kernel_launch(void* const* d_in, const int* in_sizes, int n_in,
                              void* d_out, int out_size, void* d_ws, size_t ws_size,
                              hipStream_t stream) {
  const float* x   = (const float*)d_in[0];
  const int* ei    = (const int*)d_in[1];
  const float* ew  = (const float*)d_in[2];
  const float* Wz  = (const float*)d_in[3];
  const float* bz  = (const float*)d_in[4];
  const float* Wr  = (const float*)d_in[5];
  const float* br  = (const float*)d_in[6];
  const float* Wh  = (const float*)d_in[7];
  const float* bh  = (const float*)d_in[8];
  const float* Wa  = (const float*)d_in[9];
  const float* ba  = (const float*)d_in[10];
  const float* cv  = (const float*)d_in[11];
  const float* Wfc = (const float*)d_in[12];
  const float* bfc = (const float*)d_in[13];
  float* out = (float*)d_out;

  char* w = (char*)d_ws;
  auto alloc = [&](size_t bytes) {
    char* p = w;
    w += (bytes + 255) & ~(size_t)255;
    return p;
  };
  unsigned long long* dc = (unsigned long long*)alloc((size_t)Nn * 8);
  float* dis = (float*)alloc((size_t)Nn * 4);
  int* cnt   = (int*)alloc((size_t)Nn * 4);
  int* rp    = (int*)alloc((size_t)(Nn + 1) * 4);
  int* cur   = (int*)alloc((size_t)Nn * 4);
  unsigned* epack = (unsigned*)alloc((size_t)Ee * 4);
  __half* x16  = (__half*)alloc((size_t)Nn * Ff * Tt * 2);
  __half* Px16 = (__half*)alloc((size_t)Tt * Nn * Ff * 2);
  float* h     = (float*)alloc((size_t)Nn * Hh * 4);
  __half* h16  = (__half*)alloc((size_t)Nn * Hh * 2);
  __half* rh16 = (__half*)alloc((size_t)Nn * Hh * 2);
  __half* zb16 = (__half*)alloc((size_t)Nn * Hh * 2);
  __half* Ph16 = (__half*)alloc((size_t)Nn * Hh * 2);
  __half* Prh16 = (__half*)alloc((size_t)Nn * Hh * 2);
  __half* hs16 = (__half*)alloc((size_t)Tt * Nn * Hh * 2);  // 76.8 MB history

  hipMemsetAsync(dc, 0, (size_t)Nn * 8, stream);
  hipMemsetAsync(h, 0, (size_t)Nn * Hh * 4, stream);
  hipMemsetAsync(h16, 0, (size_t)Nn * Hh * 2, stream);  // fp16 zero == 0x0000

  k_deg<<<(Ee + 255) / 256, 256, 0, stream>>>(ei, ew, dc);
  k_dis<<<(Nn + 255) / 256, 256, 0, stream>>>(dc, dis, cnt);
  k_scan<<<1, 1024, 0, stream>>>(cnt, rp, cur);
  k_scatter<<<(Ee + 255) / 256, 256, 0, stream>>>(ei, ew, dis, cur, epack);
  {
    const size_t total = (size_t)Nn * Ff * Tt;
    k_cvt_x<<<(int)((total + 255) / 256), 256, 0, stream>>>(x, x16);
  }
  k_agg_px<<<(Nn + 3) / 4, 256, 0, stream>>>(x, x16, Px16, rp, epack, dis);

  const int gGemm = (Nn + 15) / 16;  // 256-thread blocks, 16 nodes each
  const int gNode = (Nn + 3) / 4;
  for (int t = 0; t < Tt; t++) {
    k_agg64v<<<gNode, 256, 0, stream>>>(h16, Ph16, rp, epack, dis);
    k_gemm_zr<<<gGemm, 256, 0, stream>>>(Px16, Ph16, h16, Wz, bz, Wr, br, zb16, rh16, t);
    k_agg64v<<<gNode, 256, 0, stream>>>(rh16, Prh16, rp, epack, dis);
    k_gemm_h<<<gGemm, 256, 0, stream>>>(Px16, Prh16, zb16, h, h16, hs16, Wh, bh, t);
  }
  k_att<<<gNode, 256, 0, stream>>>(hs16, Wa, ba, cv, Wfc, bfc, out);
}

// Round 12
// 2781.577 us; speedup vs baseline: 1.0086x; 1.0086x over previous
//
#include <hip/hip_runtime.h>
#include <hip/hip_fp16.h>
#include <math.h>

#define Nn 50000
#define Ff 16
#define Tt 12
#define Hh 64
#define Ee 1600000
#define Cc 80  // F + H

static __device__ __forceinline__ float sigmoidf_(float x) { return 1.0f / (1.0f + expf(-x)); }

// ---------------- CSR build ----------------
// dc[d] accumulates (count << 42) + round(ew * 2^21) in one u64 atomic.
__global__ void k_deg(const int* __restrict__ ei, const float* __restrict__ ew,
                      unsigned long long* __restrict__ dc) {
  int e = blockIdx.x * blockDim.x + threadIdx.x;
  if (e >= Ee) return;
  int d = ei[Ee + e];
  unsigned long long pk = (1ULL << 42) + (unsigned long long)(ew[e] * 2097152.0f + 0.5f);
  atomicAdd(&dc[d], pk);
}

__global__ void k_dis(const unsigned long long* __restrict__ dc,
                      float* __restrict__ dis, int* __restrict__ cnt) {
  int i = blockIdx.x * blockDim.x + threadIdx.x;
  if (i >= Nn) return;
  unsigned long long v = dc[i];
  cnt[i] = (int)(v >> 42);
  float deg = (float)(v & ((1ULL << 42) - 1)) * (1.0f / 2097152.0f);
  dis[i] = 1.0f / sqrtf(deg + 1.0f);
}

__global__ __launch_bounds__(1024) void k_scan(const int* __restrict__ cnt,
                                               int* __restrict__ rp, int* __restrict__ cur) {
  __shared__ int ss[1024];
  const int ITEMS = (Nn + 1023) / 1024;  // 49
  int t = threadIdx.x;
  int base = t * ITEMS;
  int sum = 0;
  for (int k = 0; k < ITEMS; k++) {
    int idx = base + k;
    if (idx < Nn) sum += cnt[idx];
  }
  ss[t] = sum;
  __syncthreads();
  for (int off = 1; off < 1024; off <<= 1) {
    int v = (t >= off) ? ss[t - off] : 0;
    __syncthreads();
    ss[t] += v;
    __syncthreads();
  }
  int run = ss[t] - sum;  // exclusive prefix
  for (int k = 0; k < ITEMS; k++) {
    int idx = base + k;
    if (idx < Nn) { rp[idx] = run; cur[idx] = run; run += cnt[idx]; }
  }
  if (t == 0) rp[Nn] = Ee;
}

// edge2[pos] = {src, normalized weight}: one scattered 8-B store per edge
__global__ void k_scatter(const int* __restrict__ ei, const float* __restrict__ ew,
                          const float* __restrict__ dis, int* __restrict__ cur,
                          int2* __restrict__ edge2) {
  int e = blockIdx.x * blockDim.x + threadIdx.x;
  if (e >= Ee) return;
  int s = ei[e];
  int d = ei[Ee + e];
  float w = ew[e] * dis[s] * dis[d];
  int pos = atomicAdd(&cur[d], 1);
  edge2[pos] = make_int2(s, __float_as_int(w));
}

// ---------------- x fp32 -> fp16 (once) ----------------
__global__ void k_cvt_x(const float* __restrict__ x, __half* __restrict__ x16) {
  size_t idx = (size_t)blockIdx.x * blockDim.x + threadIdx.x;
  const size_t total = (size_t)Nn * Ff * Tt;
  if (idx < total) x16[idx] = __float2half(x[idx]);
}

// ---------------- Px16[t][i][f] = (A_hat @ x): wave per node, 48 lanes x 8B per edge ----------------
__global__ __launch_bounds__(256) void k_agg_px(
    const float* __restrict__ x, const __half* __restrict__ x16, __half* __restrict__ Px16,
    const int* __restrict__ rp, const int2* __restrict__ edge2,
    const float* __restrict__ dis) {
  int i = blockIdx.x * 4 + (threadIdx.x >> 6);
  if (i >= Nn) return;
  int lane = threadIdx.x & 63;
  const int R = Ff * Tt;  // 192
  const bool act = lane < 48;
  float d = dis[i], sn = d * d;
  float a0 = 0.f, a1 = 0.f, a2 = 0.f, a3 = 0.f;
  if (act) {
    float4 sv = *(const float4*)(x + (size_t)i * R + 4 * lane);  // self, fp32 exact
    a0 = sn * sv.x; a1 = sn * sv.y; a2 = sn * sv.z; a3 = sn * sv.w;
  }
  int jb = rp[i], je = rp[i + 1];
  for (int j = jb; j < je; j += 2) {
    int jc1 = min(j + 1, Ee - 1);
    int2 e0 = edge2[j];
    int2 e1 = edge2[jc1];
    float w0 = __int_as_float(e0.y);
    float w1 = (j + 1 < je) ? __int_as_float(e1.y) : 0.f;
    if (act) {
      uint2 g0 = *(const uint2*)(x16 + (size_t)e0.x * R + 4 * lane);
      uint2 g1 = *(const uint2*)(x16 + (size_t)e1.x * R + 4 * lane);
      float2 p01 = __half22float2(*reinterpret_cast<const __half2*>(&g0.x));
      float2 p23 = __half22float2(*reinterpret_cast<const __half2*>(&g0.y));
      float2 q01 = __half22float2(*reinterpret_cast<const __half2*>(&g1.x));
      float2 q23 = __half22float2(*reinterpret_cast<const __half2*>(&g1.y));
      a0 = fmaf(w0, p01.x, a0); a1 = fmaf(w0, p01.y, a1);
      a2 = fmaf(w0, p23.x, a2); a3 = fmaf(w0, p23.y, a3);
      a0 = fmaf(w1, q01.x, a0); a1 = fmaf(w1, q01.y, a1);
      a2 = fmaf(w1, q23.x, a2); a3 = fmaf(w1, q23.y, a3);
    }
  }
  if (act) {
#pragma unroll
    for (int k = 0; k < 4; k++) {
      int cch = 4 * lane + k;           // channel = f*T + t
      int f = cch / Tt, tt = cch % Tt;
      float val = (k == 0) ? a0 : (k == 1) ? a1 : (k == 2) ? a2 : a3;
      Px16[(size_t)tt * Nn * Ff + (size_t)i * Ff + f] = __float2half(val);
    }
  }
}

// ---------------- aggregation: wave per node, 16 lanes/edge x 8B, 4 edges/instr ----------------
__global__ __launch_bounds__(256) void k_agg64v(
    const __half* __restrict__ v, __half* __restrict__ outv,
    const int* __restrict__ rp, const int2* __restrict__ edge2,
    const float* __restrict__ dis) {
  int i = blockIdx.x * 4 + (threadIdx.x >> 6);
  if (i >= Nn) return;
  int lane = threadIdx.x & 63;
  int g = lane >> 4;   // edge slot 0..3
  int c = lane & 15;   // channel quad: 4c..4c+3
  float d = dis[i], sn = d * d;
  float a0, a1, a2, a3;
  {
    const uint2 gv = *(const uint2*)(v + (size_t)i * Hh + 4 * c);  // self
    float2 f01 = __half22float2(*reinterpret_cast<const __half2*>(&gv.x));
    float2 f23 = __half22float2(*reinterpret_cast<const __half2*>(&gv.y));
    float ws = (g == 0) ? sn : 0.f;
    a0 = ws * f01.x; a1 = ws * f01.y; a2 = ws * f23.x; a3 = ws * f23.y;
  }
  int jb = rp[i], je = rp[i + 1];
  for (int j0 = jb; j0 < je; j0 += 8) {
    int j1 = j0 + g;
    int j2 = j0 + 4 + g;
    int2 e1 = edge2[min(j1, Ee - 1)];
    int2 e2 = edge2[min(j2, Ee - 1)];
    float w1 = (j1 < je) ? __int_as_float(e1.y) : 0.f;
    float w2 = (j2 < je) ? __int_as_float(e2.y) : 0.f;
    const uint2 g1 = *(const uint2*)(v + (size_t)e1.x * Hh + 4 * c);
    const uint2 g2 = *(const uint2*)(v + (size_t)e2.x * Hh + 4 * c);
    float2 p01 = __half22float2(*reinterpret_cast<const __half2*>(&g1.x));
    float2 p23 = __half22float2(*reinterpret_cast<const __half2*>(&g1.y));
    float2 q01 = __half22float2(*reinterpret_cast<const __half2*>(&g2.x));
    float2 q23 = __half22float2(*reinterpret_cast<const __half2*>(&g2.y));
    a0 = fmaf(w1, p01.x, a0); a1 = fmaf(w1, p01.y, a1);
    a2 = fmaf(w1, p23.x, a2); a3 = fmaf(w1, p23.y, a3);
    a0 = fmaf(w2, q01.x, a0); a1 = fmaf(w2, q01.y, a1);
    a2 = fmaf(w2, q23.x, a2); a3 = fmaf(w2, q23.y, a3);
  }
  a0 += __shfl_xor(a0, 16, 64); a1 += __shfl_xor(a1, 16, 64);
  a2 += __shfl_xor(a2, 16, 64); a3 += __shfl_xor(a3, 16, 64);
  a0 += __shfl_xor(a0, 32, 64); a1 += __shfl_xor(a1, 32, 64);
  a2 += __shfl_xor(a2, 32, 64); a3 += __shfl_xor(a3, 32, 64);
  if (lane < 16) {
    __half2 h01, h23;
    h01.x = __float2half_rn(a0); h01.y = __float2half_rn(a1);
    h23.x = __float2half_rn(a2); h23.y = __float2half_rn(a3);
    uint2 st;
    st.x = *reinterpret_cast<unsigned int*>(&h01);
    st.y = *reinterpret_cast<unsigned int*>(&h23);
    *(uint2*)(outv + (size_t)i * Hh + 4 * c) = st;
  }
}

// shared helper: stage 16 nodes x 80 channels (fp16 sources) into fp32 LDS
static __device__ __forceinline__ void stage_x(
    float (*sX)[Cc], const __half* __restrict__ Px16t, const __half* __restrict__ P64,
    int i0, int tid) {
  if (tid < 160) {
    int n = tid / 10, r = tid % 10;
    int i = i0 + n;
    uint4 raw = make_uint4(0u, 0u, 0u, 0u);
    if (i < Nn) {
      raw = (r < 2) ? *(const uint4*)(Px16t + (size_t)i * Ff + r * 8)
                    : *(const uint4*)(P64 + (size_t)i * Hh + (r - 2) * 8);
    }
    float2 f0 = __half22float2(*reinterpret_cast<const __half2*>(&raw.x));
    float2 f1 = __half22float2(*reinterpret_cast<const __half2*>(&raw.y));
    float2 f2 = __half22float2(*reinterpret_cast<const __half2*>(&raw.z));
    float2 f3 = __half22float2(*reinterpret_cast<const __half2*>(&raw.w));
    float* dst = &sX[n][r * 8];
    dst[0] = f0.x; dst[1] = f0.y; dst[2] = f1.x; dst[3] = f1.y;
    dst[4] = f2.x; dst[5] = f2.y; dst[6] = f3.x; dst[7] = f3.y;
  }
}

// ---------------- GEMM z/r: (Wz,Wr) packed as __half2 -> 25 KB LDS, half the weight reads ----------------
// (r10 form, verified 2707 us total. No waves-per-EU hint: the 2nd __launch_bounds__
// arg forces a VGPR cap satisfied by spilling to scratch — measured r2/r6.)
__global__ __launch_bounds__(256) void k_gemm_zr(
    const __half* __restrict__ Px16, const __half* __restrict__ Ph16,
    const __half* __restrict__ h16,
    const float* __restrict__ Wz, const float* __restrict__ bz,
    const float* __restrict__ Wr, const float* __restrict__ br,
    __half* __restrict__ zb16, __half* __restrict__ rh16, int tstep) {
  __shared__ __half2 sWzr[Cc * Hh];  // 20 KB: {wz, wr} per (c,o)
  __shared__ float sX[16][Cc];       // 5 KB
  const int tid = threadIdx.x;
  const int i0 = blockIdx.x * 16;
  {
    const float4* wz4 = (const float4*)Wz;
    const float4* wr4 = (const float4*)Wr;
    for (int q = tid; q < (Cc * Hh) / 4; q += 256) {
      float4 z = wz4[q];
      float4 r = wr4[q];
      sWzr[4 * q + 0] = __floats2half2_rn(z.x, r.x);
      sWzr[4 * q + 1] = __floats2half2_rn(z.y, r.y);
      sWzr[4 * q + 2] = __floats2half2_rn(z.z, r.z);
      sWzr[4 * q + 3] = __floats2half2_rn(z.w, r.w);
    }
  }
  stage_x(sX, Px16 + (size_t)tstep * Nn * Ff, Ph16, i0, tid);
  __syncthreads();
  const int wv = tid >> 6, o = tid & 63;
  float az[4] = {0, 0, 0, 0}, ar[4] = {0, 0, 0, 0};
  for (int c = 0; c < Cc; c += 4) {
    float2 w0 = __half22float2(sWzr[(c + 0) * Hh + o]);
    float2 w1 = __half22float2(sWzr[(c + 1) * Hh + o]);
    float2 w2 = __half22float2(sWzr[(c + 2) * Hh + o]);
    float2 w3 = __half22float2(sWzr[(c + 3) * Hh + o]);
#pragma unroll
    for (int nd = 0; nd < 4; nd++) {
      const float4 xv = *(const float4*)&sX[wv * 4 + nd][c];
      az[nd] = fmaf(xv.x, w0.x, fmaf(xv.y, w1.x, fmaf(xv.z, w2.x, fmaf(xv.w, w3.x, az[nd]))));
      ar[nd] = fmaf(xv.x, w0.y, fmaf(xv.y, w1.y, fmaf(xv.z, w2.y, fmaf(xv.w, w3.y, ar[nd]))));
    }
  }
  float bzo = bz[o], bro = br[o];
#pragma unroll
  for (int nd = 0; nd < 4; nd++) {
    int i = i0 + wv * 4 + nd;
    if (i < Nn) {
      float zv = sigmoidf_(az[nd] + bzo);
      float rv = sigmoidf_(ar[nd] + bro);
      float hv = __half2float(h16[(size_t)i * Hh + o]);
      zb16[(size_t)i * Hh + o] = __float2half(zv);
      rh16[(size_t)i * Hh + o] = __float2half(rv * hv);
    }
  }
}

// ---------------- GEMM h: Wh packed as __half2 c-pairs (reads halved, 15 KB LDS) ----------------
__global__ __launch_bounds__(256) void k_gemm_h(
    const __half* __restrict__ Px16, const __half* __restrict__ Prh16,
    const __half* __restrict__ zb16, float* __restrict__ h, __half* __restrict__ h16,
    __half* __restrict__ hs16,
    const float* __restrict__ Wh, const float* __restrict__ bh, int tstep) {
  __shared__ __half2 sWh[(Cc / 2) * Hh];  // 10 KB: {Wh[c][o], Wh[c+1][o]}
  __shared__ float sX[16][Cc];            // 5 KB
  const int tid = threadIdx.x;
  const int i0 = blockIdx.x * 16;
  for (int q = tid; q < (Cc / 2) * Hh; q += 256) {
    int c2 = q / Hh, o = q % Hh;
    int c = 2 * c2;
    sWh[q] = __floats2half2_rn(Wh[c * Hh + o], Wh[(c + 1) * Hh + o]);
  }
  stage_x(sX, Px16 + (size_t)tstep * Nn * Ff, Prh16, i0, tid);
  __syncthreads();
  const int wv = tid >> 6, o = tid & 63;
  float ah[4] = {0, 0, 0, 0};
  for (int c = 0; c < Cc; c += 4) {
    float2 wa = __half22float2(sWh[(c / 2) * Hh + o]);
    float2 wb = __half22float2(sWh[(c / 2 + 1) * Hh + o]);
#pragma unroll
    for (int nd = 0; nd < 4; nd++) {
      const float4 xv = *(const float4*)&sX[wv * 4 + nd][c];
      ah[nd] = fmaf(xv.x, wa.x, fmaf(xv.y, wa.y, fmaf(xv.z, wb.x, fmaf(xv.w, wb.y, ah[nd]))));
    }
  }
  float bho = bh[o];
  __half* hst = hs16 + (size_t)tstep * Nn * Hh;
#pragma unroll
  for (int nd = 0; nd < 4; nd++) {
    int i = i0 + wv * 4 + nd;
    if (i < Nn) {
      float hc = tanhf(ah[nd] + bho);
      float zv = __half2float(zb16[(size_t)i * Hh + o]);
      float hv = h[(size_t)i * Hh + o];
      float hn = zv * hv + (1.0f - zv) * hc;
      h[(size_t)i * Hh + o] = hn;
      __half hh = __float2half(hn);
      h16[(size_t)i * Hh + o] = hh;
      hst[(size_t)i * Hh + o] = hh;
    }
  }
}

// ---------------- attention + output: wave per node over T=12 history ----------------
// Round-7 loop shape (VGPR 44, 55% occ — both interchange variants spilled, r8/r9).
// Wa packed as __half2 c-pairs: weight ds_read_b32 per c-step 4 -> 2, sWa 16->8 KB.
__global__ __launch_bounds__(256) void k_att(
    const __half* __restrict__ hs16, const float* __restrict__ Wa,
    const float* __restrict__ ba, const float* __restrict__ cv,
    const float* __restrict__ Wfc, const float* __restrict__ bfc,
    float* __restrict__ out) {
  __shared__ __half2 sWa[(Hh / 2) * Hh];  // 8 KB: {Wa[c][o], Wa[c+1][o]}
  __shared__ float sH[4][Tt][Hh];         // 12 KB
  const int tid = threadIdx.x;
  for (int q = tid; q < (Hh / 2) * Hh; q += 256) {
    int c2 = q / Hh, o = q % Hh;
    int c = 2 * c2;
    sWa[q] = __floats2half2_rn(Wa[c * Hh + o], Wa[(c + 1) * Hh + o]);
  }
  const int wv = tid >> 6, o = tid & 63;
  const int i = blockIdx.x * 4 + wv;
  if (i < Nn) {
#pragma unroll
    for (int t = 0; t < Tt; t++)
      sH[wv][t][o] = __half2float(hs16[(size_t)t * Nn * Hh + (size_t)i * Hh + o]);
  }
  __syncthreads();
  if (i >= Nn) return;
  float bao = ba[o], cvo = cv[o];
  float al[Tt];
#pragma unroll
  for (int t = 0; t < Tt; t++) {
    float sc = 0.f;
    for (int c = 0; c < Hh; c += 4) {
      const float4 hv4 = *(const float4*)&sH[wv][t][c];
      float2 wa = __half22float2(sWa[(c / 2) * Hh + o]);
      float2 wb = __half22float2(sWa[(c / 2 + 1) * Hh + o]);
      sc = fmaf(hv4.x, wa.x, fmaf(hv4.y, wa.y, fmaf(hv4.z, wb.x, fmaf(hv4.w, wb.y, sc))));
    }
    float ap = tanhf(sc + bao) * cvo;
#pragma unroll
    for (int off = 32; off >= 1; off >>= 1) ap += __shfl_xor(ap, off, 64);
    al[t] = ap;  // all lanes hold align[i][t]
  }
  float m = al[0];
#pragma unroll
  for (int t = 1; t < Tt; t++) m = fmaxf(m, al[t]);
  float s = 0.f;
#pragma unroll
  for (int t = 0; t < Tt; t++) { al[t] = expf(al[t] - m); s += al[t]; }
  float inv = 1.0f / s;
  float cx = 0.f;
#pragma unroll
  for (int t = 0; t < Tt; t++) cx = fmaf(al[t], sH[wv][t][o], cx);
  float p = cx * inv * Wfc[o];
#pragma unroll
  for (int off = 32; off >= 1; off >>= 1) p += __shfl_xor(p, off, 64);
  if (o == 0) out[i] = p + bfc[0];
}

extern "C" void kernel_launch(void* const* d_in, const int* in_sizes, int n_in,
                              void* d_out, int out_size, void* d_ws, size_t ws_size,
                              hipStream_t stream) {
  const float* x   = (const float*)d_in[0];
  const int* ei    = (const int*)d_in[1];
  const float* ew  = (const float*)d_in[2];
  const float* Wz  = (const float*)d_in[3];
  const float* bz  = (const float*)d_in[4];
  const float* Wr  = (const float*)d_in[5];
  const float* br  = (const float*)d_in[6];
  const float* Wh  = (const float*)d_in[7];
  const float* bh  = (const float*)d_in[8];
  const float* Wa  = (const float*)d_in[9];
  const float* ba  = (const float*)d_in[10];
  const float* cv  = (const float*)d_in[11];
  const float* Wfc = (const float*)d_in[12];
  const float* bfc = (const float*)d_in[13];
  float* out = (float*)d_out;

  char* w = (char*)d_ws;
  auto alloc = [&](size_t bytes) {
    char* p = w;
    w += (bytes + 255) & ~(size_t)255;
    return p;
  };
  unsigned long long* dc = (unsigned long long*)alloc((size_t)Nn * 8);
  float* dis = (float*)alloc((size_t)Nn * 4);
  int* cnt   = (int*)alloc((size_t)Nn * 4);
  int* rp    = (int*)alloc((size_t)(Nn + 1) * 4);
  int* cur   = (int*)alloc((size_t)Nn * 4);
  int2* edge2 = (int2*)alloc((size_t)Ee * 8);
  __half* x16  = (__half*)alloc((size_t)Nn * Ff * Tt * 2);
  __half* Px16 = (__half*)alloc((size_t)Tt * Nn * Ff * 2);
  float* h     = (float*)alloc((size_t)Nn * Hh * 4);
  __half* h16  = (__half*)alloc((size_t)Nn * Hh * 2);
  __half* rh16 = (__half*)alloc((size_t)Nn * Hh * 2);
  __half* zb16 = (__half*)alloc((size_t)Nn * Hh * 2);
  __half* Ph16 = (__half*)alloc((size_t)Nn * Hh * 2);
  __half* Prh16 = (__half*)alloc((size_t)Nn * Hh * 2);
  __half* hs16 = (__half*)alloc((size_t)Tt * Nn * Hh * 2);  // 76.8 MB history

  hipMemsetAsync(dc, 0, (size_t)Nn * 8, stream);
  hipMemsetAsync(h, 0, (size_t)Nn * Hh * 4, stream);
  hipMemsetAsync(h16, 0, (size_t)Nn * Hh * 2, stream);  // fp16 zero == 0x0000

  k_deg<<<(Ee + 255) / 256, 256, 0, stream>>>(ei, ew, dc);
  k_dis<<<(Nn + 255) / 256, 256, 0, stream>>>(dc, dis, cnt);
  k_scan<<<1, 1024, 0, stream>>>(cnt, rp, cur);
  k_scatter<<<(Ee + 255) / 256, 256, 0, stream>>>(ei, ew, dis, cur, edge2);
  {
    const size_t total = (size_t)Nn * Ff * Tt;
    k_cvt_x<<<(int)((total + 255) / 256), 256, 0, stream>>>(x, x16);
  }
  k_agg_px<<<(Nn + 3) / 4, 256, 0, stream>>>(x, x16, Px16, rp, edge2, dis);

  const int gGemm = (Nn + 15) / 16;  // 256-thread blocks, 16 nodes each
  const int gNode = (Nn + 3) / 4;
  for (int t = 0; t < Tt; t++) {
    k_agg64v<<<gNode, 256, 0, stream>>>(h16, Ph16, rp, edge2, dis);
    k_gemm_zr<<<gGemm, 256, 0, stream>>>(Px16, Ph16, h16, Wz, bz, Wr, br, zb16, rh16, t);
    k_agg64v<<<gNode, 256, 0, stream>>>(rh16, Prh16, rp, edge2, dis);
    k_gemm_h<<<gGemm, 256, 0, stream>>>(Px16, Prh16, zb16, h, h16, hs16, Wh, bh, t);
  }
  k_att<<<gNode, 256, 0, stream>>>(hs16, Wa, ba, cv, Wfc, bfc, out);
}

// Round 13
// 2633.047 us; speedup vs baseline: 1.0655x; 1.0564x over previous
//
#include <hip/hip_runtime.h>
#include <hip/hip_fp16.h>
#include <math.h>

#define Nn 50000
#define Ff 16
#define Tt 12
#define Hh 64
#define Ee 1600000
#define Cc 80  // F + H

static __device__ __forceinline__ float sigmoidf_(float x) { return 1.0f / (1.0f + expf(-x)); }

// ---------------- CSR build ----------------
// dc[d] accumulates (count << 42) + round(ew * 2^21) in one u64 atomic.
__global__ void k_deg(const int* __restrict__ ei, const float* __restrict__ ew,
                      unsigned long long* __restrict__ dc) {
  int e = blockIdx.x * blockDim.x + threadIdx.x;
  if (e >= Ee) return;
  int d = ei[Ee + e];
  unsigned long long pk = (1ULL << 42) + (unsigned long long)(ew[e] * 2097152.0f + 0.5f);
  atomicAdd(&dc[d], pk);
}

__global__ void k_dis(const unsigned long long* __restrict__ dc,
                      float* __restrict__ dis, int* __restrict__ cnt) {
  int i = blockIdx.x * blockDim.x + threadIdx.x;
  if (i >= Nn) return;
  unsigned long long v = dc[i];
  cnt[i] = (int)(v >> 42);
  float deg = (float)(v & ((1ULL << 42) - 1)) * (1.0f / 2097152.0f);
  dis[i] = 1.0f / sqrtf(deg + 1.0f);
}

__global__ __launch_bounds__(1024) void k_scan(const int* __restrict__ cnt,
                                               int* __restrict__ rp, int* __restrict__ cur) {
  __shared__ int ss[1024];
  const int ITEMS = (Nn + 1023) / 1024;  // 49
  int t = threadIdx.x;
  int base = t * ITEMS;
  int sum = 0;
  for (int k = 0; k < ITEMS; k++) {
    int idx = base + k;
    if (idx < Nn) sum += cnt[idx];
  }
  ss[t] = sum;
  __syncthreads();
  for (int off = 1; off < 1024; off <<= 1) {
    int v = (t >= off) ? ss[t - off] : 0;
    __syncthreads();
    ss[t] += v;
    __syncthreads();
  }
  int run = ss[t] - sum;  // exclusive prefix
  for (int k = 0; k < ITEMS; k++) {
    int idx = base + k;
    if (idx < Nn) { rp[idx] = run; cur[idx] = run; run += cnt[idx]; }
  }
  if (t == 0) rp[Nn] = Ee;
}

// edge2[pos] = {src, normalized weight}: one scattered 8-B store per edge
__global__ void k_scatter(const int* __restrict__ ei, const float* __restrict__ ew,
                          const float* __restrict__ dis, int* __restrict__ cur,
                          int2* __restrict__ edge2) {
  int e = blockIdx.x * blockDim.x + threadIdx.x;
  if (e >= Ee) return;
  int s = ei[e];
  int d = ei[Ee + e];
  float w = ew[e] * dis[s] * dis[d];
  int pos = atomicAdd(&cur[d], 1);
  edge2[pos] = make_int2(s, __float_as_int(w));
}

// ---------------- x fp32 -> fp16 (once) ----------------
__global__ void k_cvt_x(const float* __restrict__ x, __half* __restrict__ x16) {
  size_t idx = (size_t)blockIdx.x * blockDim.x + threadIdx.x;
  const size_t total = (size_t)Nn * Ff * Tt;
  if (idx < total) x16[idx] = __float2half(x[idx]);
}

// ---------------- Px16[t][i][f] = (A_hat @ x): wave per node, 48 lanes x 8B per edge ----------------
__global__ __launch_bounds__(256) void k_agg_px(
    const float* __restrict__ x, const __half* __restrict__ x16, __half* __restrict__ Px16,
    const int* __restrict__ rp, const int2* __restrict__ edge2,
    const float* __restrict__ dis) {
  int i = blockIdx.x * 4 + (threadIdx.x >> 6);
  if (i >= Nn) return;
  int lane = threadIdx.x & 63;
  const int R = Ff * Tt;  // 192
  const bool act = lane < 48;
  float d = dis[i], sn = d * d;
  float a0 = 0.f, a1 = 0.f, a2 = 0.f, a3 = 0.f;
  if (act) {
    float4 sv = *(const float4*)(x + (size_t)i * R + 4 * lane);  // self, fp32 exact
    a0 = sn * sv.x; a1 = sn * sv.y; a2 = sn * sv.z; a3 = sn * sv.w;
  }
  int jb = rp[i], je = rp[i + 1];
  for (int j = jb; j < je; j += 2) {
    int jc1 = min(j + 1, Ee - 1);
    int2 e0 = edge2[j];
    int2 e1 = edge2[jc1];
    float w0 = __int_as_float(e0.y);
    float w1 = (j + 1 < je) ? __int_as_float(e1.y) : 0.f;
    if (act) {
      uint2 g0 = *(const uint2*)(x16 + (size_t)e0.x * R + 4 * lane);
      uint2 g1 = *(const uint2*)(x16 + (size_t)e1.x * R + 4 * lane);
      float2 p01 = __half22float2(*reinterpret_cast<const __half2*>(&g0.x));
      float2 p23 = __half22float2(*reinterpret_cast<const __half2*>(&g0.y));
      float2 q01 = __half22float2(*reinterpret_cast<const __half2*>(&g1.x));
      float2 q23 = __half22float2(*reinterpret_cast<const __half2*>(&g1.y));
      a0 = fmaf(w0, p01.x, a0); a1 = fmaf(w0, p01.y, a1);
      a2 = fmaf(w0, p23.x, a2); a3 = fmaf(w0, p23.y, a3);
      a0 = fmaf(w1, q01.x, a0); a1 = fmaf(w1, q01.y, a1);
      a2 = fmaf(w1, q23.x, a2); a3 = fmaf(w1, q23.y, a3);
    }
  }
  if (act) {
#pragma unroll
    for (int k = 0; k < 4; k++) {
      int cch = 4 * lane + k;           // channel = f*T + t
      int f = cch / Tt, tt = cch % Tt;
      float val = (k == 0) ? a0 : (k == 1) ? a1 : (k == 2) ? a2 : a3;
      Px16[(size_t)tt * Nn * Ff + (size_t)i * Ff + f] = __float2half(val);
    }
  }
}

// ---------------- aggregation: wave per node, 16 lanes/edge x 8B, 16 edges/iteration ----------------
// (r13: unrolled 8 -> 16 edges per iteration to double loads-in-flight per wave;
//  gather is latency-bound: ~6 us L2-BW floor, ~17 us issue floor, 51 us observed)
__global__ __launch_bounds__(256) void k_agg64v(
    const __half* __restrict__ v, __half* __restrict__ outv,
    const int* __restrict__ rp, const int2* __restrict__ edge2,
    const float* __restrict__ dis) {
  int i = blockIdx.x * 4 + (threadIdx.x >> 6);
  if (i >= Nn) return;
  int lane = threadIdx.x & 63;
  int g = lane >> 4;   // edge slot 0..3
  int c = lane & 15;   // channel quad: 4c..4c+3
  float d = dis[i], sn = d * d;
  float a0, a1, a2, a3;
  {
    const uint2 gv = *(const uint2*)(v + (size_t)i * Hh + 4 * c);  // self
    float2 f01 = __half22float2(*reinterpret_cast<const __half2*>(&gv.x));
    float2 f23 = __half22float2(*reinterpret_cast<const __half2*>(&gv.y));
    float ws = (g == 0) ? sn : 0.f;
    a0 = ws * f01.x; a1 = ws * f01.y; a2 = ws * f23.x; a3 = ws * f23.y;
  }
  int jb = rp[i], je = rp[i + 1];
  for (int j0 = jb; j0 < je; j0 += 16) {
    int j1 = j0 + g;
    int j2 = j0 + 4 + g;
    int j3 = j0 + 8 + g;
    int j4 = j0 + 12 + g;
    int2 e1 = edge2[min(j1, Ee - 1)];
    int2 e2 = edge2[min(j2, Ee - 1)];
    int2 e3 = edge2[min(j3, Ee - 1)];
    int2 e4 = edge2[min(j4, Ee - 1)];
    float w1 = (j1 < je) ? __int_as_float(e1.y) : 0.f;
    float w2 = (j2 < je) ? __int_as_float(e2.y) : 0.f;
    float w3 = (j3 < je) ? __int_as_float(e3.y) : 0.f;
    float w4 = (j4 < je) ? __int_as_float(e4.y) : 0.f;
    const uint2 g1 = *(const uint2*)(v + (size_t)e1.x * Hh + 4 * c);
    const uint2 g2 = *(const uint2*)(v + (size_t)e2.x * Hh + 4 * c);
    const uint2 g3 = *(const uint2*)(v + (size_t)e3.x * Hh + 4 * c);
    const uint2 g4 = *(const uint2*)(v + (size_t)e4.x * Hh + 4 * c);
    float2 p01 = __half22float2(*reinterpret_cast<const __half2*>(&g1.x));
    float2 p23 = __half22float2(*reinterpret_cast<const __half2*>(&g1.y));
    float2 q01 = __half22float2(*reinterpret_cast<const __half2*>(&g2.x));
    float2 q23 = __half22float2(*reinterpret_cast<const __half2*>(&g2.y));
    float2 r01 = __half22float2(*reinterpret_cast<const __half2*>(&g3.x));
    float2 r23 = __half22float2(*reinterpret_cast<const __half2*>(&g3.y));
    float2 s01 = __half22float2(*reinterpret_cast<const __half2*>(&g4.x));
    float2 s23 = __half22float2(*reinterpret_cast<const __half2*>(&g4.y));
    a0 = fmaf(w1, p01.x, a0); a1 = fmaf(w1, p01.y, a1);
    a2 = fmaf(w1, p23.x, a2); a3 = fmaf(w1, p23.y, a3);
    a0 = fmaf(w2, q01.x, a0); a1 = fmaf(w2, q01.y, a1);
    a2 = fmaf(w2, q23.x, a2); a3 = fmaf(w2, q23.y, a3);
    a0 = fmaf(w3, r01.x, a0); a1 = fmaf(w3, r01.y, a1);
    a2 = fmaf(w3, r23.x, a2); a3 = fmaf(w3, r23.y, a3);
    a0 = fmaf(w4, s01.x, a0); a1 = fmaf(w4, s01.y, a1);
    a2 = fmaf(w4, s23.x, a2); a3 = fmaf(w4, s23.y, a3);
  }
  a0 += __shfl_xor(a0, 16, 64); a1 += __shfl_xor(a1, 16, 64);
  a2 += __shfl_xor(a2, 16, 64); a3 += __shfl_xor(a3, 16, 64);
  a0 += __shfl_xor(a0, 32, 64); a1 += __shfl_xor(a1, 32, 64);
  a2 += __shfl_xor(a2, 32, 64); a3 += __shfl_xor(a3, 32, 64);
  if (lane < 16) {
    __half2 h01, h23;
    h01.x = __float2half_rn(a0); h01.y = __float2half_rn(a1);
    h23.x = __float2half_rn(a2); h23.y = __float2half_rn(a3);
    uint2 st;
    st.x = *reinterpret_cast<unsigned int*>(&h01);
    st.y = *reinterpret_cast<unsigned int*>(&h23);
    *(uint2*)(outv + (size_t)i * Hh + 4 * c) = st;
  }
}

// shared helper: stage 16 nodes x 80 channels (fp16 sources) into fp32 LDS
static __device__ __forceinline__ void stage_x(
    float (*sX)[Cc], const __half* __restrict__ Px16t, const __half* __restrict__ P64,
    int i0, int tid) {
  if (tid < 160) {
    int n = tid / 10, r = tid % 10;
    int i = i0 + n;
    uint4 raw = make_uint4(0u, 0u, 0u, 0u);
    if (i < Nn) {
      raw = (r < 2) ? *(const uint4*)(Px16t + (size_t)i * Ff + r * 8)
                    : *(const uint4*)(P64 + (size_t)i * Hh + (r - 2) * 8);
    }
    float2 f0 = __half22float2(*reinterpret_cast<const __half2*>(&raw.x));
    float2 f1 = __half22float2(*reinterpret_cast<const __half2*>(&raw.y));
    float2 f2 = __half22float2(*reinterpret_cast<const __half2*>(&raw.z));
    float2 f3 = __half22float2(*reinterpret_cast<const __half2*>(&raw.w));
    float* dst = &sX[n][r * 8];
    dst[0] = f0.x; dst[1] = f0.y; dst[2] = f1.x; dst[3] = f1.y;
    dst[4] = f2.x; dst[5] = f2.y; dst[6] = f3.x; dst[7] = f3.y;
  }
}

// ---------------- GEMM z/r: (Wz,Wr) packed as __half2 -> 25 KB LDS (crosses 3->6 blocks/CU) ----------------
// (r10 form, verified. No waves-per-EU hint: the 2nd __launch_bounds__ arg forces a
// VGPR cap satisfied by spilling to scratch — measured r2/r6.)
__global__ __launch_bounds__(256) void k_gemm_zr(
    const __half* __restrict__ Px16, const __half* __restrict__ Ph16,
    const __half* __restrict__ h16,
    const float* __restrict__ Wz, const float* __restrict__ bz,
    const float* __restrict__ Wr, const float* __restrict__ br,
    __half* __restrict__ zb16, __half* __restrict__ rh16, int tstep) {
  __shared__ __half2 sWzr[Cc * Hh];  // 20 KB: {wz, wr} per (c,o)
  __shared__ float sX[16][Cc];       // 5 KB
  const int tid = threadIdx.x;
  const int i0 = blockIdx.x * 16;
  {
    const float4* wz4 = (const float4*)Wz;
    const float4* wr4 = (const float4*)Wr;
    for (int q = tid; q < (Cc * Hh) / 4; q += 256) {
      float4 z = wz4[q];
      float4 r = wr4[q];
      sWzr[4 * q + 0] = __floats2half2_rn(z.x, r.x);
      sWzr[4 * q + 1] = __floats2half2_rn(z.y, r.y);
      sWzr[4 * q + 2] = __floats2half2_rn(z.z, r.z);
      sWzr[4 * q + 3] = __floats2half2_rn(z.w, r.w);
    }
  }
  stage_x(sX, Px16 + (size_t)tstep * Nn * Ff, Ph16, i0, tid);
  __syncthreads();
  const int wv = tid >> 6, o = tid & 63;
  float az[4] = {0, 0, 0, 0}, ar[4] = {0, 0, 0, 0};
  for (int c = 0; c < Cc; c += 4) {
    float2 w0 = __half22float2(sWzr[(c + 0) * Hh + o]);
    float2 w1 = __half22float2(sWzr[(c + 1) * Hh + o]);
    float2 w2 = __half22float2(sWzr[(c + 2) * Hh + o]);
    float2 w3 = __half22float2(sWzr[(c + 3) * Hh + o]);
#pragma unroll
    for (int nd = 0; nd < 4; nd++) {
      const float4 xv = *(const float4*)&sX[wv * 4 + nd][c];
      az[nd] = fmaf(xv.x, w0.x, fmaf(xv.y, w1.x, fmaf(xv.z, w2.x, fmaf(xv.w, w3.x, az[nd]))));
      ar[nd] = fmaf(xv.x, w0.y, fmaf(xv.y, w1.y, fmaf(xv.z, w2.y, fmaf(xv.w, w3.y, ar[nd]))));
    }
  }
  float bzo = bz[o], bro = br[o];
#pragma unroll
  for (int nd = 0; nd < 4; nd++) {
    int i = i0 + wv * 4 + nd;
    if (i < Nn) {
      float zv = sigmoidf_(az[nd] + bzo);
      float rv = sigmoidf_(ar[nd] + bro);
      float hv = __half2float(h16[(size_t)i * Hh + o]);
      zb16[(size_t)i * Hh + o] = __float2half(zv);
      rh16[(size_t)i * Hh + o] = __float2half(rv * hv);
    }
  }
}

// ---------------- GEMM h: fp32 Wh (r10 form — r12's fp16 c-pair packing regressed +11us/dispatch:
// no occupancy gain at 25KB LDS, unpack cvt on critical path) ----------------
__global__ __launch_bounds__(256) void k_gemm_h(
    const __half* __restrict__ Px16, const __half* __restrict__ Prh16,
    const __half* __restrict__ zb16, float* __restrict__ h, __half* __restrict__ h16,
    __half* __restrict__ hs16,
    const float* __restrict__ Wh, const float* __restrict__ bh, int tstep) {
  __shared__ float sWh[Cc * Hh];    // 20 KB
  __shared__ float sX[16][Cc];      // 5 KB
  const int tid = threadIdx.x;
  const int i0 = blockIdx.x * 16;
  {
    const float4* w4 = (const float4*)Wh;
    float4* s4 = (float4*)sWh;
    for (int q = tid; q < (Cc * Hh) / 4; q += 256) s4[q] = w4[q];
  }
  stage_x(sX, Px16 + (size_t)tstep * Nn * Ff, Prh16, i0, tid);
  __syncthreads();
  const int wv = tid >> 6, o = tid & 63;
  float ah[4] = {0, 0, 0, 0};
  for (int c = 0; c < Cc; c += 4) {
    float w0 = sWh[(c + 0) * Hh + o], w1 = sWh[(c + 1) * Hh + o];
    float w2 = sWh[(c + 2) * Hh + o], w3 = sWh[(c + 3) * Hh + o];
#pragma unroll
    for (int nd = 0; nd < 4; nd++) {
      const float4 xv = *(const float4*)&sX[wv * 4 + nd][c];
      ah[nd] = fmaf(xv.x, w0, fmaf(xv.y, w1, fmaf(xv.z, w2, fmaf(xv.w, w3, ah[nd]))));
    }
  }
  float bho = bh[o];
  __half* hst = hs16 + (size_t)tstep * Nn * Hh;
#pragma unroll
  for (int nd = 0; nd < 4; nd++) {
    int i = i0 + wv * 4 + nd;
    if (i < Nn) {
      float hc = tanhf(ah[nd] + bho);
      float zv = __half2float(zb16[(size_t)i * Hh + o]);
      float hv = h[(size_t)i * Hh + o];
      float hn = zv * hv + (1.0f - zv) * hc;
      h[(size_t)i * Hh + o] = hn;
      __half hh = __float2half(hn);
      h16[(size_t)i * Hh + o] = hh;
      hst[(size_t)i * Hh + o] = hh;
    }
  }
}

// ---------------- attention + output: wave per node over T=12 history ----------------
// r12 form, verified 205us / VGPR 32 / 82% occ: Wa packed __half2 c-pairs (2 reads/c-step).
__global__ __launch_bounds__(256) void k_att(
    const __half* __restrict__ hs16, const float* __restrict__ Wa,
    const float* __restrict__ ba, const float* __restrict__ cv,
    const float* __restrict__ Wfc, const float* __restrict__ bfc,
    float* __restrict__ out) {
  __shared__ __half2 sWa[(Hh / 2) * Hh];  // 8 KB: {Wa[c][o], Wa[c+1][o]}
  __shared__ float sH[4][Tt][Hh];         // 12 KB
  const int tid = threadIdx.x;
  for (int q = tid; q < (Hh / 2) * Hh; q += 256) {
    int c2 = q / Hh, o = q % Hh;
    int c = 2 * c2;
    sWa[q] = __floats2half2_rn(Wa[c * Hh + o], Wa[(c + 1) * Hh + o]);
  }
  const int wv = tid >> 6, o = tid & 63;
  const int i = blockIdx.x * 4 + wv;
  if (i < Nn) {
#pragma unroll
    for (int t = 0; t < Tt; t++)
      sH[wv][t][o] = __half2float(hs16[(size_t)t * Nn * Hh + (size_t)i * Hh + o]);
  }
  __syncthreads();
  if (i >= Nn) return;
  float bao = ba[o], cvo = cv[o];
  float al[Tt];
#pragma unroll
  for (int t = 0; t < Tt; t++) {
    float sc = 0.f;
    for (int c = 0; c < Hh; c += 4) {
      const float4 hv4 = *(const float4*)&sH[wv][t][c];
      float2 wa = __half22float2(sWa[(c / 2) * Hh + o]);
      float2 wb = __half22float2(sWa[(c / 2 + 1) * Hh + o]);
      sc = fmaf(hv4.x, wa.x, fmaf(hv4.y, wa.y, fmaf(hv4.z, wb.x, fmaf(hv4.w, wb.y, sc))));
    }
    float ap = tanhf(sc + bao) * cvo;
#pragma unroll
    for (int off = 32; off >= 1; off >>= 1) ap += __shfl_xor(ap, off, 64);
    al[t] = ap;  // all lanes hold align[i][t]
  }
  float m = al[0];
#pragma unroll
  for (int t = 1; t < Tt; t++) m = fmaxf(m, al[t]);
  float s = 0.f;
#pragma unroll
  for (int t = 0; t < Tt; t++) { al[t] = expf(al[t] - m); s += al[t]; }
  float inv = 1.0f / s;
  float cx = 0.f;
#pragma unroll
  for (int t = 0; t < Tt; t++) cx = fmaf(al[t], sH[wv][t][o], cx);
  float p = cx * inv * Wfc[o];
#pragma unroll
  for (int off = 32; off >= 1; off >>= 1) p += __shfl_xor(p, off, 64);
  if (o == 0) out[i] = p + bfc[0];
}

extern "C" void kernel_launch(void* const* d_in, const int* in_sizes, int n_in,
                              void* d_out, int out_size, void* d_ws, size_t ws_size,
                              hipStream_t stream) {
  const float* x   = (const float*)d_in[0];
  const int* ei    = (const int*)d_in[1];
  const float* ew  = (const float*)d_in[2];
  const float* Wz  = (const float*)d_in[3];
  const float* bz  = (const float*)d_in[4];
  const float* Wr  = (const float*)d_in[5];
  const float* br  = (const float*)d_in[6];
  const float* Wh  = (const float*)d_in[7];
  const float* bh  = (const float*)d_in[8];
  const float* Wa  = (const float*)d_in[9];
  const float* ba  = (const float*)d_in[10];
  const float* cv  = (const float*)d_in[11];
  const float* Wfc = (const float*)d_in[12];
  const float* bfc = (const float*)d_in[13];
  float* out = (float*)d_out;

  char* w = (char*)d_ws;
  auto alloc = [&](size_t bytes) {
    char* p = w;
    w += (bytes + 255) & ~(size_t)255;
    return p;
  };
  unsigned long long* dc = (unsigned long long*)alloc((size_t)Nn * 8);
  float* dis = (float*)alloc((size_t)Nn * 4);
  int* cnt   = (int*)alloc((size_t)Nn * 4);
  int* rp    = (int*)alloc((size_t)(Nn + 1) * 4);
  int* cur   = (int*)alloc((size_t)Nn * 4);
  int2* edge2 = (int2*)alloc((size_t)Ee * 8);
  __half* x16  = (__half*)alloc((size_t)Nn * Ff * Tt * 2);
  __half* Px16 = (__half*)alloc((size_t)Tt * Nn * Ff * 2);
  float* h     = (float*)alloc((size_t)Nn * Hh * 4);
  __half* h16  = (__half*)alloc((size_t)Nn * Hh * 2);
  __half* rh16 = (__half*)alloc((size_t)Nn * Hh * 2);
  __half* zb16 = (__half*)alloc((size_t)Nn * Hh * 2);
  __half* Ph16 = (__half*)alloc((size_t)Nn * Hh * 2);
  __half* Prh16 = (__half*)alloc((size_t)Nn * Hh * 2);
  __half* hs16 = (__half*)alloc((size_t)Tt * Nn * Hh * 2);  // 76.8 MB history

  hipMemsetAsync(dc, 0, (size_t)Nn * 8, stream);
  hipMemsetAsync(h, 0, (size_t)Nn * Hh * 4, stream);
  hipMemsetAsync(h16, 0, (size_t)Nn * Hh * 2, stream);  // fp16 zero == 0x0000

  k_deg<<<(Ee + 255) / 256, 256, 0, stream>>>(ei, ew, dc);
  k_dis<<<(Nn + 255) / 256, 256, 0, stream>>>(dc, dis, cnt);
  k_scan<<<1, 1024, 0, stream>>>(cnt, rp, cur);
  k_scatter<<<(Ee + 255) / 256, 256, 0, stream>>>(ei, ew, dis, cur, edge2);
  {
    const size_t total = (size_t)Nn * Ff * Tt;
    k_cvt_x<<<(int)((total + 255) / 256), 256, 0, stream>>>(x, x16);
  }
  k_agg_px<<<(Nn + 3) / 4, 256, 0, stream>>>(x, x16, Px16, rp, edge2, dis);

  const int gGemm = (Nn + 15) / 16;  // 256-thread blocks, 16 nodes each
  const int gNode = (Nn + 3) / 4;
  for (int t = 0; t < Tt; t++) {
    k_agg64v<<<gNode, 256, 0, stream>>>(h16, Ph16, rp, edge2, dis);
    k_gemm_zr<<<gGemm, 256, 0, stream>>>(Px16, Ph16, h16, Wz, bz, Wr, br, zb16, rh16, t);
    k_agg64v<<<gNode, 256, 0, stream>>>(rh16, Prh16, rp, edge2, dis);
    k_gemm_h<<<gGemm, 256, 0, stream>>>(Px16, Prh16, zb16, h, h16, hs16, Wh, bh, t);
  }
  k_att<<<gNode, 256, 0, stream>>>(hs16, Wa, ba, cv, Wfc, bfc, out);
}

// Round 14
// 1789.686 us; speedup vs baseline: 1.5675x; 1.4712x over previous
//
#include <hip/hip_runtime.h>
#include <hip/hip_fp16.h>
#include <math.h>

#define Nn 50000
#define Ff 16
#define Tt 12
#define Hh 64
#define Ee 1600000
#define Cc 80  // F + H

typedef _Float16 f16x8 __attribute__((ext_vector_type(8)));
typedef float f32x4 __attribute__((ext_vector_type(4)));

static __device__ __forceinline__ float sigmoidf_(float x) { return 1.0f / (1.0f + expf(-x)); }

// ---------------- CSR build ----------------
// dc[d] accumulates (count << 42) + round(ew * 2^21) in one u64 atomic.
__global__ void k_deg(const int* __restrict__ ei, const float* __restrict__ ew,
                      unsigned long long* __restrict__ dc) {
  int e = blockIdx.x * blockDim.x + threadIdx.x;
  if (e >= Ee) return;
  int d = ei[Ee + e];
  unsigned long long pk = (1ULL << 42) + (unsigned long long)(ew[e] * 2097152.0f + 0.5f);
  atomicAdd(&dc[d], pk);
}

__global__ void k_dis(const unsigned long long* __restrict__ dc,
                      float* __restrict__ dis, int* __restrict__ cnt) {
  int i = blockIdx.x * blockDim.x + threadIdx.x;
  if (i >= Nn) return;
  unsigned long long v = dc[i];
  cnt[i] = (int)(v >> 42);
  float deg = (float)(v & ((1ULL << 42) - 1)) * (1.0f / 2097152.0f);
  dis[i] = 1.0f / sqrtf(deg + 1.0f);
}

__global__ __launch_bounds__(1024) void k_scan(const int* __restrict__ cnt,
                                               int* __restrict__ rp, int* __restrict__ cur) {
  __shared__ int ss[1024];
  const int ITEMS = (Nn + 1023) / 1024;  // 49
  int t = threadIdx.x;
  int base = t * ITEMS;
  int sum = 0;
  for (int k = 0; k < ITEMS; k++) {
    int idx = base + k;
    if (idx < Nn) sum += cnt[idx];
  }
  ss[t] = sum;
  __syncthreads();
  for (int off = 1; off < 1024; off <<= 1) {
    int v = (t >= off) ? ss[t - off] : 0;
    __syncthreads();
    ss[t] += v;
    __syncthreads();
  }
  int run = ss[t] - sum;  // exclusive prefix
  for (int k = 0; k < ITEMS; k++) {
    int idx = base + k;
    if (idx < Nn) { rp[idx] = run; cur[idx] = run; run += cnt[idx]; }
  }
  if (t == 0) rp[Nn] = Ee;
}

// edge2[pos] = {src, normalized weight}: one scattered 8-B store per edge
__global__ void k_scatter(const int* __restrict__ ei, const float* __restrict__ ew,
                          const float* __restrict__ dis, int* __restrict__ cur,
                          int2* __restrict__ edge2) {
  int e = blockIdx.x * blockDim.x + threadIdx.x;
  if (e >= Ee) return;
  int s = ei[e];
  int d = ei[Ee + e];
  float w = ew[e] * dis[s] * dis[d];
  int pos = atomicAdd(&cur[d], 1);
  edge2[pos] = make_int2(s, __float_as_int(w));
}

// ---------------- x fp32 -> fp16 (once) ----------------
__global__ void k_cvt_x(const float* __restrict__ x, __half* __restrict__ x16) {
  size_t idx = (size_t)blockIdx.x * blockDim.x + threadIdx.x;
  const size_t total = (size_t)Nn * Ff * Tt;
  if (idx < total) x16[idx] = __float2half(x[idx]);
}

// ---------------- weight fragments for MFMA (once) ----------------
// slot s: 0-3 = Wz tiles, 4-7 = Wr tiles, 8-11 = Wh tiles; n0 = (s&3)*16.
// frag[((s*3+ks)*64 + lane)*8 + j] = W[k][n0 + (lane&15)], k = ks*32 + (lane>>4)*8 + j (0 if k>=80)
__global__ void k_wfrag(const float* __restrict__ Wz, const float* __restrict__ Wr,
                        const float* __restrict__ Wh, __half* __restrict__ frag) {
  int t = blockIdx.x * 256 + threadIdx.x;
  if (t >= 12 * 3 * 64) return;
  int s = t / 192, rem = t % 192, ks = rem / 64, lane = rem % 64;
  int q = lane >> 4, nl = lane & 15;
  const float* W = (s < 4) ? Wz : (s < 8) ? Wr : Wh;
  int n0 = (s & 3) * 16;
  __half tmp[8];
#pragma unroll
  for (int j = 0; j < 8; j++) {
    int k = ks * 32 + q * 8 + j;
    float v = (k < Cc) ? W[k * Hh + n0 + nl] : 0.f;
    tmp[j] = __float2half(v);
  }
  *(uint4*)(frag + ((size_t)(s * 3 + ks) * 64 + lane) * 8) = *(uint4*)tmp;
}

// ---------------- Px16[t][i][f] = (A_hat @ x): wave per node, 48 lanes x 8B per edge ----------------
__global__ __launch_bounds__(256) void k_agg_px(
    const float* __restrict__ x, const __half* __restrict__ x16, __half* __restrict__ Px16,
    const int* __restrict__ rp, const int2* __restrict__ edge2,
    const float* __restrict__ dis) {
  int i = blockIdx.x * 4 + (threadIdx.x >> 6);
  if (i >= Nn) return;
  int lane = threadIdx.x & 63;
  const int R = Ff * Tt;  // 192
  const bool act = lane < 48;
  float d = dis[i], sn = d * d;
  float a0 = 0.f, a1 = 0.f, a2 = 0.f, a3 = 0.f;
  if (act) {
    float4 sv = *(const float4*)(x + (size_t)i * R + 4 * lane);  // self, fp32 exact
    a0 = sn * sv.x; a1 = sn * sv.y; a2 = sn * sv.z; a3 = sn * sv.w;
  }
  int jb = rp[i], je = rp[i + 1];
  for (int j = jb; j < je; j += 2) {
    int jc1 = min(j + 1, Ee - 1);
    int2 e0 = edge2[j];
    int2 e1 = edge2[jc1];
    float w0 = __int_as_float(e0.y);
    float w1 = (j + 1 < je) ? __int_as_float(e1.y) : 0.f;
    if (act) {
      uint2 g0 = *(const uint2*)(x16 + (size_t)e0.x * R + 4 * lane);
      uint2 g1 = *(const uint2*)(x16 + (size_t)e1.x * R + 4 * lane);
      float2 p01 = __half22float2(*reinterpret_cast<const __half2*>(&g0.x));
      float2 p23 = __half22float2(*reinterpret_cast<const __half2*>(&g0.y));
      float2 q01 = __half22float2(*reinterpret_cast<const __half2*>(&g1.x));
      float2 q23 = __half22float2(*reinterpret_cast<const __half2*>(&g1.y));
      a0 = fmaf(w0, p01.x, a0); a1 = fmaf(w0, p01.y, a1);
      a2 = fmaf(w0, p23.x, a2); a3 = fmaf(w0, p23.y, a3);
      a0 = fmaf(w1, q01.x, a0); a1 = fmaf(w1, q01.y, a1);
      a2 = fmaf(w1, q23.x, a2); a3 = fmaf(w1, q23.y, a3);
    }
  }
  if (act) {
#pragma unroll
    for (int k = 0; k < 4; k++) {
      int cch = 4 * lane + k;           // channel = f*T + t
      int f = cch / Tt, tt = cch % Tt;
      float val = (k == 0) ? a0 : (k == 1) ? a1 : (k == 2) ? a2 : a3;
      Px16[(size_t)tt * Nn * Ff + (size_t)i * Ff + f] = __float2half(val);
    }
  }
}

// ---------------- aggregation: wave per node, 16 lanes/edge x 8B, 16 edges/iteration ----------------
__global__ __launch_bounds__(256) void k_agg64v(
    const __half* __restrict__ v, __half* __restrict__ outv,
    const int* __restrict__ rp, const int2* __restrict__ edge2,
    const float* __restrict__ dis) {
  int i = blockIdx.x * 4 + (threadIdx.x >> 6);
  if (i >= Nn) return;
  int lane = threadIdx.x & 63;
  int g = lane >> 4;   // edge slot 0..3
  int c = lane & 15;   // channel quad: 4c..4c+3
  float d = dis[i], sn = d * d;
  float a0, a1, a2, a3;
  {
    const uint2 gv = *(const uint2*)(v + (size_t)i * Hh + 4 * c);  // self
    float2 f01 = __half22float2(*reinterpret_cast<const __half2*>(&gv.x));
    float2 f23 = __half22float2(*reinterpret_cast<const __half2*>(&gv.y));
    float ws = (g == 0) ? sn : 0.f;
    a0 = ws * f01.x; a1 = ws * f01.y; a2 = ws * f23.x; a3 = ws * f23.y;
  }
  int jb = rp[i], je = rp[i + 1];
  for (int j0 = jb; j0 < je; j0 += 16) {
    int j1 = j0 + g;
    int j2 = j0 + 4 + g;
    int j3 = j0 + 8 + g;
    int j4 = j0 + 12 + g;
    int2 e1 = edge2[min(j1, Ee - 1)];
    int2 e2 = edge2[min(j2, Ee - 1)];
    int2 e3 = edge2[min(j3, Ee - 1)];
    int2 e4 = edge2[min(j4, Ee - 1)];
    float w1 = (j1 < je) ? __int_as_float(e1.y) : 0.f;
    float w2 = (j2 < je) ? __int_as_float(e2.y) : 0.f;
    float w3 = (j3 < je) ? __int_as_float(e3.y) : 0.f;
    float w4 = (j4 < je) ? __int_as_float(e4.y) : 0.f;
    const uint2 g1 = *(const uint2*)(v + (size_t)e1.x * Hh + 4 * c);
    const uint2 g2 = *(const uint2*)(v + (size_t)e2.x * Hh + 4 * c);
    const uint2 g3 = *(const uint2*)(v + (size_t)e3.x * Hh + 4 * c);
    const uint2 g4 = *(const uint2*)(v + (size_t)e4.x * Hh + 4 * c);
    float2 p01 = __half22float2(*reinterpret_cast<const __half2*>(&g1.x));
    float2 p23 = __half22float2(*reinterpret_cast<const __half2*>(&g1.y));
    float2 q01 = __half22float2(*reinterpret_cast<const __half2*>(&g2.x));
    float2 q23 = __half22float2(*reinterpret_cast<const __half2*>(&g2.y));
    float2 r01 = __half22float2(*reinterpret_cast<const __half2*>(&g3.x));
    float2 r23 = __half22float2(*reinterpret_cast<const __half2*>(&g3.y));
    float2 s01 = __half22float2(*reinterpret_cast<const __half2*>(&g4.x));
    float2 s23 = __half22float2(*reinterpret_cast<const __half2*>(&g4.y));
    a0 = fmaf(w1, p01.x, a0); a1 = fmaf(w1, p01.y, a1);
    a2 = fmaf(w1, p23.x, a2); a3 = fmaf(w1, p23.y, a3);
    a0 = fmaf(w2, q01.x, a0); a1 = fmaf(w2, q01.y, a1);
    a2 = fmaf(w2, q23.x, a2); a3 = fmaf(w2, q23.y, a3);
    a0 = fmaf(w3, r01.x, a0); a1 = fmaf(w3, r01.y, a1);
    a2 = fmaf(w3, r23.x, a2); a3 = fmaf(w3, r23.y, a3);
    a0 = fmaf(w4, s01.x, a0); a1 = fmaf(w4, s01.y, a1);
    a2 = fmaf(w4, s23.x, a2); a3 = fmaf(w4, s23.y, a3);
  }
  a0 += __shfl_xor(a0, 16, 64); a1 += __shfl_xor(a1, 16, 64);
  a2 += __shfl_xor(a2, 16, 64); a3 += __shfl_xor(a3, 16, 64);
  a0 += __shfl_xor(a0, 32, 64); a1 += __shfl_xor(a1, 32, 64);
  a2 += __shfl_xor(a2, 32, 64); a3 += __shfl_xor(a3, 32, 64);
  if (lane < 16) {
    __half2 h01, h23;
    h01.x = __float2half_rn(a0); h01.y = __float2half_rn(a1);
    h23.x = __float2half_rn(a2); h23.y = __float2half_rn(a3);
    uint2 st;
    st.x = *reinterpret_cast<unsigned int*>(&h01);
    st.y = *reinterpret_cast<unsigned int*>(&h23);
    *(uint2*)(outv + (size_t)i * Hh + 4 * c) = st;
  }
}

// ---- shared fp16 staging: 16 nodes x 104 halves (row = [Px(16) | P64(64) | zeros(24)]) ----
// Row stride 104 halves (208 B): a_frag ds_read_b128 lands 2 lanes/bank (free).
static __device__ __forceinline__ void stage_x16(
    __half* sX16, const __half* __restrict__ Px16t, const __half* __restrict__ P64,
    int i0, int tid) {
  if (tid < 160) {
    int n = tid / 10, r = tid % 10;
    int i = i0 + n;
    uint4 raw = (r < 2) ? *(const uint4*)(Px16t + (size_t)i * Ff + r * 8)
                        : *(const uint4*)(P64 + (size_t)i * Hh + (r - 2) * 8);
    *(uint4*)(sX16 + n * 104 + r * 8) = raw;
  } else if (tid < 208) {
    int p = tid - 160, n = p / 3, part = p % 3;
    *(uint4*)(sX16 + n * 104 + 80 + part * 8) = make_uint4(0u, 0u, 0u, 0u);
  }
}

// ---------------- GEMM z/r via MFMA 16x16x32 f16: block = 16 nodes, wave w -> out tile w ----------------
// A: X[node][c] (LDS, fp16). B: weight frags (global, pre-swizzled). K = 80 padded to 96 (3 MFMA).
// Layouts [verified per guide m89/m120]: A[m=lane&15][k=(lane>>4)*8+j]; C/D col=lane&15, row=(lane>>4)*4+reg.
// NOTE: no waves-per-EU hint (2nd __launch_bounds__ arg => scratch spill disaster, r2/r6).
__global__ __launch_bounds__(256) void k_gemm_zr(
    const __half* __restrict__ Px16, const __half* __restrict__ Ph16,
    const __half* __restrict__ h16, const __half* __restrict__ frag,
    const float* __restrict__ bz, const float* __restrict__ br,
    __half* __restrict__ zb16, __half* __restrict__ rh16, int tstep) {
  __shared__ __align__(16) __half sX16[16 * 104];
  const int tid = threadIdx.x;
  const int i0 = blockIdx.x * 16;  // Nn = 3125*16 exactly, no guards
  const int wv = tid >> 6, lane = tid & 63;
  // b-fragments: z = slot wv, r = slot 4+wv (coalesced b128 loads, L2-resident)
  f16x8 bzf[3], brf[3];
#pragma unroll
  for (int ks = 0; ks < 3; ks++) {
    bzf[ks] = *(const f16x8*)(frag + ((size_t)(wv * 3 + ks) * 64 + lane) * 8);
    brf[ks] = *(const f16x8*)(frag + ((size_t)((4 + wv) * 3 + ks) * 64 + lane) * 8);
  }
  stage_x16(sX16, Px16 + (size_t)tstep * Nn * Ff, Ph16, i0, tid);
  __syncthreads();
  const int m = lane & 15, q = lane >> 4;
  f32x4 accz = {0.f, 0.f, 0.f, 0.f}, accr = {0.f, 0.f, 0.f, 0.f};
#pragma unroll
  for (int ks = 0; ks < 3; ks++) {
    f16x8 a = *(const f16x8*)(sX16 + m * 104 + ks * 32 + q * 8);
    accz = __builtin_amdgcn_mfma_f32_16x16x32_f16(a, bzf[ks], accz, 0, 0, 0);
    accr = __builtin_amdgcn_mfma_f32_16x16x32_f16(a, brf[ks], accr, 0, 0, 0);
  }
  const int o = wv * 16 + m;
  float bzo = bz[o], bro = br[o];
  const int nb = i0 + q * 4;
#pragma unroll
  for (int r = 0; r < 4; r++) {
    int node = nb + r;
    float zv = sigmoidf_(accz[r] + bzo);
    float rv = sigmoidf_(accr[r] + bro);
    float hv = __half2float(h16[(size_t)node * Hh + o]);
    zb16[(size_t)node * Hh + o] = __float2half(zv);
    rh16[(size_t)node * Hh + o] = __float2half(rv * hv);
  }
}

// ---------------- GEMM h via MFMA + GRU update: wave w -> out tile w (slot 8+w) ----------------
__global__ __launch_bounds__(256) void k_gemm_h(
    const __half* __restrict__ Px16, const __half* __restrict__ Prh16,
    const __half* __restrict__ zb16, float* __restrict__ h, __half* __restrict__ h16,
    __half* __restrict__ hs16, const __half* __restrict__ frag,
    const float* __restrict__ bh, int tstep) {
  __shared__ __align__(16) __half sX16[16 * 104];
  const int tid = threadIdx.x;
  const int i0 = blockIdx.x * 16;
  const int wv = tid >> 6, lane = tid & 63;
  f16x8 bf[3];
#pragma unroll
  for (int ks = 0; ks < 3; ks++)
    bf[ks] = *(const f16x8*)(frag + ((size_t)((8 + wv) * 3 + ks) * 64 + lane) * 8);
  stage_x16(sX16, Px16 + (size_t)tstep * Nn * Ff, Prh16, i0, tid);
  __syncthreads();
  const int m = lane & 15, q = lane >> 4;
  f32x4 acc = {0.f, 0.f, 0.f, 0.f};
#pragma unroll
  for (int ks = 0; ks < 3; ks++) {
    f16x8 a = *(const f16x8*)(sX16 + m * 104 + ks * 32 + q * 8);
    acc = __builtin_amdgcn_mfma_f32_16x16x32_f16(a, bf[ks], acc, 0, 0, 0);
  }
  const int o = wv * 16 + m;
  float bho = bh[o];
  const int nb = i0 + q * 4;
  __half* hst = hs16 + (size_t)tstep * Nn * Hh;
#pragma unroll
  for (int r = 0; r < 4; r++) {
    int node = nb + r;
    float hc = tanhf(acc[r] + bho);
    float zv = __half2float(zb16[(size_t)node * Hh + o]);
    float hv = h[(size_t)node * Hh + o];
    float hn = zv * hv + (1.0f - zv) * hc;
    h[(size_t)node * Hh + o] = hn;
    __half hh = __float2half(hn);
    h16[(size_t)node * Hh + o] = hh;
    hst[(size_t)node * Hh + o] = hh;
  }
}

// ---------------- attention + output: wave per node over T=12 history ----------------
// r12 form, verified 205-210us / VGPR 32 / 84% occ: Wa packed __half2 c-pairs.
__global__ __launch_bounds__(256) void k_att(
    const __half* __restrict__ hs16, const float* __restrict__ Wa,
    const float* __restrict__ ba, const float* __restrict__ cv,
    const float* __restrict__ Wfc, const float* __restrict__ bfc,
    float* __restrict__ out) {
  __shared__ __half2 sWa[(Hh / 2) * Hh];  // 8 KB: {Wa[c][o], Wa[c+1][o]}
  __shared__ float sH[4][Tt][Hh];         // 12 KB
  const int tid = threadIdx.x;
  for (int q = tid; q < (Hh / 2) * Hh; q += 256) {
    int c2 = q / Hh, o = q % Hh;
    int c = 2 * c2;
    sWa[q] = __floats2half2_rn(Wa[c * Hh + o], Wa[(c + 1) * Hh + o]);
  }
  const int wv = tid >> 6, o = tid & 63;
  const int i = blockIdx.x * 4 + wv;
  if (i < Nn) {
#pragma unroll
    for (int t = 0; t < Tt; t++)
      sH[wv][t][o] = __half2float(hs16[(size_t)t * Nn * Hh + (size_t)i * Hh + o]);
  }
  __syncthreads();
  if (i >= Nn) return;
  float bao = ba[o], cvo = cv[o];
  float al[Tt];
#pragma unroll
  for (int t = 0; t < Tt; t++) {
    float sc = 0.f;
    for (int c = 0; c < Hh; c += 4) {
      const float4 hv4 = *(const float4*)&sH[wv][t][c];
      float2 wa = __half22float2(sWa[(c / 2) * Hh + o]);
      float2 wb = __half22float2(sWa[(c / 2 + 1) * Hh + o]);
      sc = fmaf(hv4.x, wa.x, fmaf(hv4.y, wa.y, fmaf(hv4.z, wb.x, fmaf(hv4.w, wb.y, sc))));
    }
    float ap = tanhf(sc + bao) * cvo;
#pragma unroll
    for (int off = 32; off >= 1; off >>= 1) ap += __shfl_xor(ap, off, 64);
    al[t] = ap;  // all lanes hold align[i][t]
  }
  float m = al[0];
#pragma unroll
  for (int t = 1; t < Tt; t++) m = fmaxf(m, al[t]);
  float s = 0.f;
#pragma unroll
  for (int t = 0; t < Tt; t++) { al[t] = expf(al[t] - m); s += al[t]; }
  float inv = 1.0f / s;
  float cx = 0.f;
#pragma unroll
  for (int t = 0; t < Tt; t++) cx = fmaf(al[t], sH[wv][t][o], cx);
  float p = cx * inv * Wfc[o];
#pragma unroll
  for (int off = 32; off >= 1; off >>= 1) p += __shfl_xor(p, off, 64);
  if (o == 0) out[i] = p + bfc[0];
}

extern "C" void kernel_launch(void* const* d_in, const int* in_sizes, int n_in,
                              void* d_out, int out_size, void* d_ws, size_t ws_size,
                              hipStream_t stream) {
  const float* x   = (const float*)d_in[0];
  const int* ei    = (const int*)d_in[1];
  const float* ew  = (const float*)d_in[2];
  const float* Wz  = (const float*)d_in[3];
  const float* bz  = (const float*)d_in[4];
  const float* Wr  = (const float*)d_in[5];
  const float* br  = (const float*)d_in[6];
  const float* Wh  = (const float*)d_in[7];
  const float* bh  = (const float*)d_in[8];
  const float* Wa  = (const float*)d_in[9];
  const float* ba  = (const float*)d_in[10];
  const float* cv  = (const float*)d_in[11];
  const float* Wfc = (const float*)d_in[12];
  const float* bfc = (const float*)d_in[13];
  float* out = (float*)d_out;

  char* w = (char*)d_ws;
  auto alloc = [&](size_t bytes) {
    char* p = w;
    w += (bytes + 255) & ~(size_t)255;
    return p;
  };
  unsigned long long* dc = (unsigned long long*)alloc((size_t)Nn * 8);
  float* dis = (float*)alloc((size_t)Nn * 4);
  int* cnt   = (int*)alloc((size_t)Nn * 4);
  int* rp    = (int*)alloc((size_t)(Nn + 1) * 4);
  int* cur   = (int*)alloc((size_t)Nn * 4);
  int2* edge2 = (int2*)alloc((size_t)Ee * 8);
  __half* x16  = (__half*)alloc((size_t)Nn * Ff * Tt * 2);
  __half* Px16 = (__half*)alloc((size_t)Tt * Nn * Ff * 2);
  float* h     = (float*)alloc((size_t)Nn * Hh * 4);
  __half* h16  = (__half*)alloc((size_t)Nn * Hh * 2);
  __half* rh16 = (__half*)alloc((size_t)Nn * Hh * 2);
  __half* zb16 = (__half*)alloc((size_t)Nn * Hh * 2);
  __half* Ph16 = (__half*)alloc((size_t)Nn * Hh * 2);
  __half* Prh16 = (__half*)alloc((size_t)Nn * Hh * 2);
  __half* hs16 = (__half*)alloc((size_t)Tt * Nn * Hh * 2);  // 76.8 MB history
  __half* wfrag = (__half*)alloc((size_t)12 * 3 * 64 * 8 * 2);  // 36.9 KB frag weights

  hipMemsetAsync(dc, 0, (size_t)Nn * 8, stream);
  hipMemsetAsync(h, 0, (size_t)Nn * Hh * 4, stream);
  hipMemsetAsync(h16, 0, (size_t)Nn * Hh * 2, stream);  // fp16 zero == 0x0000

  k_deg<<<(Ee + 255) / 256, 256, 0, stream>>>(ei, ew, dc);
  k_dis<<<(Nn + 255) / 256, 256, 0, stream>>>(dc, dis, cnt);
  k_scan<<<1, 1024, 0, stream>>>(cnt, rp, cur);
  k_scatter<<<(Ee + 255) / 256, 256, 0, stream>>>(ei, ew, dis, cur, edge2);
  {
    const size_t total = (size_t)Nn * Ff * Tt;
    k_cvt_x<<<(int)((total + 255) / 256), 256, 0, stream>>>(x, x16);
  }
  k_wfrag<<<9, 256, 0, stream>>>(Wz, Wr, Wh, wfrag);
  k_agg_px<<<(Nn + 3) / 4, 256, 0, stream>>>(x, x16, Px16, rp, edge2, dis);

  const int gGemm = Nn / 16;  // 3125 blocks, 16 nodes each (exact)
  const int gNode = (Nn + 3) / 4;
  for (int t = 0; t < Tt; t++) {
    k_agg64v<<<gNode, 256, 0, stream>>>(h16, Ph16, rp, edge2, dis);
    k_gemm_zr<<<gGemm, 256, 0, stream>>>(Px16, Ph16, h16, wfrag, bz, br, zb16, rh16, t);
    k_agg64v<<<gNode, 256, 0, stream>>>(rh16, Prh16, rp, edge2, dis);
    k_gemm_h<<<gGemm, 256, 0, stream>>>(Px16, Prh16, zb16, h, h16, hs16, wfrag, bh, t);
  }
  k_att<<<gNode, 256, 0, stream>>>(hs16, Wa, ba, cv, Wfc, bfc, out);
}